// Round 4
// baseline (51.394 us; speedup 1.0000x reference)
//
#include <hip/hip_runtime.h>

// Spherical harmonics (lmax=3, normalize=True, component normalization)
// over edge vectors. pos: [N,3] f32; edge_index: [2,E] int; out: [E,16] f32.
//
// Two-kernel pipeline:
//  1) pad_kernel: pos [N,3] -> float4 table [N,4] in d_ws (16B-aligned rows),
//     so each node gather is ONE global_load_dwordx4 touching exactly one
//     64B line per lane (vs 3 scalar dword gathers = 3x the TA transactions).
//  2) sh_edge_kernel: 1 thread/edge, 2 dwordx4 gathers, compute SH, swizzled
//     LDS transpose, block streams 16KB tile out as coalesced float4 stores.

#define SQ3f 1.7320508075688772f
#define SQ5f 2.2360679774997896f
#define SQ7f 2.6457513110645907f
#define C30f 0.9128709291752769f   // sqrt(5/6)
#define C32f 0.6123724356957945f   // sqrt(3/8)

__global__ __launch_bounds__(256) void pad_kernel(
    const float* __restrict__ pos,
    float4* __restrict__ pos4,
    int N)
{
    int i = blockIdx.x * blockDim.x + threadIdx.x;
    if (i < N) {
        pos4[i] = make_float4(pos[3 * i + 0], pos[3 * i + 1], pos[3 * i + 2], 0.0f);
    }
}

template <bool PADDED>
__global__ __launch_bounds__(256) void sh_edge_kernel(
    const float* __restrict__ pos,      // [N,3] packed (used when !PADDED)
    const float4* __restrict__ pos4,    // [N] padded  (used when PADDED)
    const int* __restrict__ eidx,
    float4* __restrict__ out4,
    int E)
{
    __shared__ float lds[256 * 16];   // 16 KB

    const int t = threadIdx.x;
    const long long blk = blockIdx.x;
    const long long e = blk * 256 + t;

    if (e < E) {
        int s = eidx[e];       // sender (row 0)
        int d = eidx[E + e];   // receiver (row 1)

        float vx, vy, vz;
        if (PADDED) {
            float4 ps = pos4[s];
            float4 pd = pos4[d];
            vx = ps.x - pd.x;
            vy = ps.y - pd.y;
            vz = ps.z - pd.z;
        } else {
            vx = pos[3 * s + 0] - pos[3 * d + 0];
            vy = pos[3 * s + 1] - pos[3 * d + 1];
            vz = pos[3 * s + 2] - pos[3 * d + 2];
        }

        float r2 = vx * vx + vy * vy + vz * vz;
        float r = sqrtf(r2);
        float inv = 1.0f / fmaxf(r, 1e-12f);   // matches reference max(r, EPS)

        float x = vx * inv;
        float y = vy * inv;
        float z = vz * inv;

        float x2 = x * x;
        float y2 = y * y;
        float z2 = z * z;
        float x2z2 = x2 + z2;

        float s20 = SQ3f * x * z;
        float s21 = SQ3f * x * y;
        float s22 = y2 - 0.5f * x2z2;
        float s23 = SQ3f * y * z;
        float s24 = 0.5f * SQ3f * (z2 - x2);

        float fy2 = 4.0f * y2 - x2z2;

        float s30 = C30f * (s20 * z + s24 * x);
        float s31 = SQ5f * s20 * y;
        float s32 = C32f * fy2 * x;
        float s33 = 0.5f * y * (2.0f * y2 - 3.0f * x2z2);
        float s34 = C32f * z * fy2;
        float s35 = SQ5f * s24 * y;
        float s36 = C30f * (s24 * z - s20 * x);

        float4 val[4];
        val[0] = make_float4(1.0f,        SQ3f * x,   SQ3f * y,   SQ3f * z);
        val[1] = make_float4(SQ5f * s20,  SQ5f * s21, SQ5f * s22, SQ5f * s23);
        val[2] = make_float4(SQ5f * s24,  SQ7f * s30, SQ7f * s31, SQ7f * s32);
        val[3] = make_float4(SQ7f * s33,  SQ7f * s34, SQ7f * s35, SQ7f * s36);

        #pragma unroll
        for (int q = 0; q < 4; ++q) {
            int col = q ^ ((t >> 1) & 3);
            *reinterpret_cast<float4*>(&lds[t * 16 + 4 * col]) = val[q];
        }
    }

    __syncthreads();

    // Stream the block's 1024 float4s out, coalesced.
    const size_t base4 = (size_t)blk * 1024;
    const size_t total4 = (size_t)E * 4;
    #pragma unroll
    for (int j = 0; j < 4; ++j) {
        int k = j * 256 + t;             // 0..1023 within the tile
        int r = k >> 2;                  // source LDS row (edge within block)
        int qq = k & 3;                  // float4 slot within that row
        int col = qq ^ ((r >> 1) & 3);   // undo swizzle
        float4 v = *reinterpret_cast<const float4*>(&lds[r * 16 + 4 * col]);
        size_t o = base4 + k;
        if (o < total4) out4[o] = v;
    }
}

extern "C" void kernel_launch(void* const* d_in, const int* in_sizes, int n_in,
                              void* d_out, int out_size, void* d_ws, size_t ws_size,
                              hipStream_t stream)
{
    const float* pos = (const float*)d_in[0];
    const int* eidx = (const int*)d_in[1];
    float4* out4 = (float4*)d_out;

    int N = in_sizes[0] / 3;
    int E = in_sizes[1] / 2;
    int block = 256;
    int grid = (int)(((long long)E + block - 1) / block);

    size_t need = (size_t)N * sizeof(float4);
    if (ws_size >= need) {
        float4* pos4 = (float4*)d_ws;
        int gpad = (N + block - 1) / block;
        pad_kernel<<<gpad, block, 0, stream>>>(pos, pos4, N);
        sh_edge_kernel<true><<<grid, block, 0, stream>>>(pos, pos4, eidx, out4, E);
    } else {
        sh_edge_kernel<false><<<grid, block, 0, stream>>>(pos, nullptr, eidx, out4, E);
    }
}

// Round 5
// 43.848 us; speedup vs baseline: 1.1721x; 1.1721x over previous
//
#include <hip/hip_runtime.h>

// Spherical harmonics (lmax=3, normalize=True, component normalization)
// over edge vectors. pos: [N,3] f32; edge_index: [2,E] int; out: [E,16] f32.
//
// 1 thread per edge, swizzled-LDS transpose, coalesced NONTEMPORAL output
// stores (output is write-once/never-read: bypass L2/L3 allocation so the
// 200MB stream doesn't churn the caches the pos-gathers live in).

#define SQ3f 1.7320508075688772f
#define SQ5f 2.2360679774997896f
#define SQ7f 2.6457513110645907f
#define C30f 0.9128709291752769f   // sqrt(5/6)
#define C32f 0.6123724356957945f   // sqrt(3/8)

typedef float f32x4 __attribute__((ext_vector_type(4)));

__global__ __launch_bounds__(256) void sh_edge_kernel(
    const float* __restrict__ pos,
    const int* __restrict__ eidx,
    f32x4* __restrict__ out4,
    int E)
{
    __shared__ float lds[256 * 16];   // 16 KB

    const int t = threadIdx.x;
    const long long blk = blockIdx.x;
    const long long e = blk * 256 + t;

    if (e < E) {
        int s = eidx[e];       // sender (row 0)
        int d = eidx[E + e];   // receiver (row 1)

        float vx = pos[3 * s + 0] - pos[3 * d + 0];
        float vy = pos[3 * s + 1] - pos[3 * d + 1];
        float vz = pos[3 * s + 2] - pos[3 * d + 2];

        float r2 = vx * vx + vy * vy + vz * vz;
        float r = sqrtf(r2);
        float inv = 1.0f / fmaxf(r, 1e-12f);   // matches reference max(r, EPS)

        float x = vx * inv;
        float y = vy * inv;
        float z = vz * inv;

        float x2 = x * x;
        float y2 = y * y;
        float z2 = z * z;
        float x2z2 = x2 + z2;

        float s20 = SQ3f * x * z;
        float s21 = SQ3f * x * y;
        float s22 = y2 - 0.5f * x2z2;
        float s23 = SQ3f * y * z;
        float s24 = 0.5f * SQ3f * (z2 - x2);

        float fy2 = 4.0f * y2 - x2z2;

        float s30 = C30f * (s20 * z + s24 * x);
        float s31 = SQ5f * s20 * y;
        float s32 = C32f * fy2 * x;
        float s33 = 0.5f * y * (2.0f * y2 - 3.0f * x2z2);
        float s34 = C32f * z * fy2;
        float s35 = SQ5f * s24 * y;
        float s36 = C30f * (s24 * z - s20 * x);

        float4 val[4];
        val[0] = make_float4(1.0f,        SQ3f * x,   SQ3f * y,   SQ3f * z);
        val[1] = make_float4(SQ5f * s20,  SQ5f * s21, SQ5f * s22, SQ5f * s23);
        val[2] = make_float4(SQ5f * s24,  SQ7f * s30, SQ7f * s31, SQ7f * s32);
        val[3] = make_float4(SQ7f * s33,  SQ7f * s34, SQ7f * s35, SQ7f * s36);

        #pragma unroll
        for (int q = 0; q < 4; ++q) {
            int col = q ^ ((t >> 1) & 3);
            *reinterpret_cast<float4*>(&lds[t * 16 + 4 * col]) = val[q];
        }
    }

    __syncthreads();

    // Stream the block's 1024 float4s out, coalesced + nontemporal.
    const size_t base4 = (size_t)blk * 1024;
    const size_t total4 = (size_t)E * 4;
    #pragma unroll
    for (int j = 0; j < 4; ++j) {
        int k = j * 256 + t;             // 0..1023 within the tile
        int r = k >> 2;                  // source LDS row (edge within block)
        int qq = k & 3;                  // float4 slot within that row
        int col = qq ^ ((r >> 1) & 3);   // undo swizzle
        f32x4 v = *reinterpret_cast<const f32x4*>(&lds[r * 16 + 4 * col]);
        size_t o = base4 + k;
        if (o < total4) {
            __builtin_nontemporal_store(v, &out4[o]);
        }
    }
}

extern "C" void kernel_launch(void* const* d_in, const int* in_sizes, int n_in,
                              void* d_out, int out_size, void* d_ws, size_t ws_size,
                              hipStream_t stream)
{
    const float* pos = (const float*)d_in[0];
    const int* eidx = (const int*)d_in[1];
    f32x4* out4 = (f32x4*)d_out;

    int E = in_sizes[1] / 2;
    int block = 256;
    int grid = (int)(((long long)E + block - 1) / block);
    sh_edge_kernel<<<grid, block, 0, stream>>>(pos, eidx, out4, E);
}